// Round 13
// baseline (136.213 us; speedup 1.0000x reference)
//
#include <hip/hip_runtime.h>

typedef unsigned short u16;
typedef __bf16 bf16x8 __attribute__((ext_vector_type(8)));
typedef __bf16 bf16x2 __attribute__((ext_vector_type(2)));
typedef unsigned short u16x8 __attribute__((ext_vector_type(8)));
typedef float f32x4 __attribute__((ext_vector_type(4)));
typedef int i32x4 __attribute__((ext_vector_type(4)));

#define MFMA16(a, b, c) __builtin_amdgcn_mfma_f32_16x16x32_bf16(a, b, c, 0, 0, 0)

#define GLDS16(gp, lp)                                                         \
  __builtin_amdgcn_global_load_lds(                                            \
      (const __attribute__((address_space(1))) unsigned int*)(gp),             \
      (__attribute__((address_space(3))) unsigned int*)(lp), 16, 0, 0)

__device__ __forceinline__ u16 f2bf(float f) {
  unsigned int u = __builtin_bit_cast(unsigned int, f);
  u += 0x7fffu + ((u >> 16) & 1u);
  return (u16)(u >> 16);
}

__device__ __forceinline__ f32x4 vmax4(f32x4 a, f32x4 b) {
  f32x4 r;
  r[0] = fmaxf(a[0], b[0]); r[1] = fmaxf(a[1], b[1]);
  r[2] = fmaxf(a[2], b[2]); r[3] = fmaxf(a[3], b[3]);
  return r;
}

// Q pre-scale: 1/sqrt(64) * log2(e)  (scores produced directly in log2 domain)
#define QSCALE 0.1803368842048386f

// ---------------- elementwise fp32 -> bf16 ----------------
__global__ void convert_x_kernel(const float* __restrict__ src,
                                 u16* __restrict__ dst, int n4) {
  int i = blockIdx.x * 256 + threadIdx.x;
  if (i < n4) {
    float4 v = ((const float4*)src)[i];
    ushort4 o;
    o.x = f2bf(v.x); o.y = f2bf(v.y); o.z = f2bf(v.z); o.w = f2bf(v.w);
    ((ushort4*)dst)[i] = o;
  }
}

// ---------------- transpose fp32 [K][N] -> bf16 [N][K] ----------------
__global__ void transpose_w_kernel(const float* __restrict__ src,
                                   u16* __restrict__ dst, int K, int N) {
  __shared__ float tile[32][33];
  const int n0 = blockIdx.x * 32, k0 = blockIdx.y * 32;
  const int t = threadIdx.x;
  const int r = t >> 3, c = (t & 7) * 4;
  float4 v = *(const float4*)&src[(size_t)(k0 + r) * N + n0 + c];
  tile[r][c + 0] = v.x; tile[r][c + 1] = v.y;
  tile[r][c + 2] = v.z; tile[r][c + 3] = v.w;
  __syncthreads();
  ushort4 o;
  o.x = f2bf(tile[c + 0][r]); o.y = f2bf(tile[c + 1][r]);
  o.z = f2bf(tile[c + 2][r]); o.w = f2bf(tile[c + 3][r]);
  *(ushort4*)&dst[(size_t)(n0 + r) * K + k0 + c] = o;
}

// ---------------- GEMM 128x128: A[M][K] bf16 rm, Bt[N][K] bf16 (B^T) --------
// qkv epilogue: Q,K head-split [b][h][s][d] (+bias, Q*=QSCALE);
// V stored TRANSPOSED [b][h][d][s] via per-wave LDS 16x17 transpose so the
// global stores are 32B-contiguous along s (write amp 8x -> 2x).
__global__ __launch_bounds__(256) void gemm_qkv_kernel(
    const u16* __restrict__ A, const u16* __restrict__ Bt,
    const float* __restrict__ bias, u16* __restrict__ Qo,
    u16* __restrict__ Ko, u16* __restrict__ VoT, int K) {
  __shared__ __align__(16) u16 As[128 * 32];
  __shared__ __align__(16) u16 Bs[128 * 32];
  const int t = threadIdx.x;
  const int lane = t & 63;
  const int l15 = lane & 15, g = lane >> 4;
  const int w = t >> 6, wr = w >> 1, wc = w & 1;
  const int m0 = blockIdx.x * 128, n0 = blockIdx.y * 128;
  const int ar = t >> 2, ak = (t & 3) * 8;
  u16* AsW = As + (t & ~63) * 8;
  u16* BsW = Bs + (t & ~63) * 8;
  const u16* Ag = A + (size_t)(m0 + ar) * K + ak;
  const u16* Bg = Bt + (size_t)(n0 + ar) * K + ak;

  f32x4 acc[4][4] = {};
  for (int k0 = 0; k0 < K; k0 += 32) {
    __syncthreads();
    GLDS16(Ag + k0, AsW);
    GLDS16(Ag + (size_t)64 * K + k0, AsW + 2048);
    GLDS16(Bg + k0, BsW);
    GLDS16(Bg + (size_t)64 * K + k0, BsW + 2048);
    __syncthreads();
    bf16x8 af[4], bfr[4];
#pragma unroll
    for (int i = 0; i < 4; ++i)
      af[i] = *(const bf16x8*)&As[(wr * 64 + i * 16 + l15) * 32 + g * 8];
#pragma unroll
    for (int j = 0; j < 4; ++j)
      bfr[j] = *(const bf16x8*)&Bs[(wc * 64 + j * 16 + l15) * 32 + g * 8];
#pragma unroll
    for (int i = 0; i < 4; ++i)
#pragma unroll
      for (int j = 0; j < 4; ++j)
        acc[i][j] = MFMA16(af[i], bfr[j], acc[i][j]);
  }

  const int part = n0 >> 10;  // uniform per block (128-wide blocks)
  if (part == 2) {
    // ---- V^T epilogue with per-wave LDS transpose ----
    __syncthreads();  // As/Bs staging reads done; reuse as scratch
    // per-wave scratch: 2 x 272 floats (double-buffered by j-parity)
    float* scr0 = (w < 2) ? (float*)As : (float*)Bs;
    float* scrw = scr0 + (w & 1) * 544;
    const int f0 = n0 - 2048;
    const int hh = (f0 >> 6) + wc;
    const int bq = m0 >> 11;
    const int dl = lane >> 2, scx = lane & 3;
#pragma unroll
    for (int i = 0; i < 4; ++i) {
#pragma unroll
      for (int j = 0; j < 4; ++j) {
        float* scr = scrw + (j & 1) * 272;
        const float bv = bias[n0 + wc * 64 + j * 16 + l15];
#pragma unroll
        for (int r = 0; r < 4; ++r)
          scr[(g * 4 + r) * 17 + l15] = acc[i][j][r] + bv;
        // wave-internal; LDS ops complete in order per wave (lgkm)
        ushort4 o;
        o.x = f2bf(scr[(scx * 4 + 0) * 17 + dl]);
        o.y = f2bf(scr[(scx * 4 + 1) * 17 + dl]);
        o.z = f2bf(scr[(scx * 4 + 2) * 17 + dl]);
        o.w = f2bf(scr[(scx * 4 + 3) * 17 + dl]);
        const int d = j * 16 + dl;
        const int s = m0 + wr * 64 + i * 16 + scx * 4;
        const int bq2 = s >> 11, sl = s & 2047;
        *(ushort4*)&VoT[(((size_t)(bq2 * 16 + hh)) * 64 + d) * 2048 + sl] = o;
      }
    }
    (void)bq;
  } else {
#pragma unroll
    for (int j = 0; j < 4; ++j) {
      const int n = n0 + wc * 64 + j * 16 + l15;
      const float bv = bias[n];
      const int f = n & 1023;
      const int hh = f >> 6, d = f & 63;
#pragma unroll
      for (int i = 0; i < 4; ++i) {
        const int mbase = m0 + wr * 64 + i * 16 + g * 4;
        const int bq = mbase >> 11, s = mbase & 2047;
        u16* dst = (part == 0) ? Qo : Ko;
        const float sc = (part == 0) ? QSCALE : 1.f;
#pragma unroll
        for (int r = 0; r < 4; ++r)
          dst[(((size_t)(bq * 16 + hh)) * 2048 + (s + r)) * 64 + d] =
              f2bf((acc[i][j][r] + bv) * sc);
      }
    }
  }
}

// ---------------- GEMM 128x128 (proj): fp32 out[M][N], +bias ----------------
// grid (M/128, N/128) = (32, 8) = 256 blocks = exactly 1/CU.
__global__ __launch_bounds__(256) void gemm_proj_kernel(
    const u16* __restrict__ A, const u16* __restrict__ Bt,
    const float* __restrict__ bias, float* __restrict__ outF, int N, int K) {
  __shared__ __align__(16) u16 As[128 * 32];
  __shared__ __align__(16) u16 Bs[128 * 32];
  const int t = threadIdx.x;
  const int lane = t & 63;
  const int l15 = lane & 15, g = lane >> 4;
  const int w = t >> 6, wr = w >> 1, wc = w & 1;
  const int m0 = blockIdx.x * 128, n0 = blockIdx.y * 128;
  const int ar = t >> 2, ak = (t & 3) * 8;
  u16* AsW = As + (t & ~63) * 8;
  u16* BsW = Bs + (t & ~63) * 8;
  const u16* Ag = A + (size_t)(m0 + ar) * K + ak;
  const u16* Bg = Bt + (size_t)(n0 + ar) * K + ak;

  f32x4 acc[4][4] = {};
  for (int k0 = 0; k0 < K; k0 += 32) {
    __syncthreads();
    GLDS16(Ag + k0, AsW);
    GLDS16(Ag + (size_t)64 * K + k0, AsW + 2048);
    GLDS16(Bg + k0, BsW);
    GLDS16(Bg + (size_t)64 * K + k0, BsW + 2048);
    __syncthreads();
    bf16x8 af[4], bfr[4];
#pragma unroll
    for (int i = 0; i < 4; ++i)
      af[i] = *(const bf16x8*)&As[(wr * 64 + i * 16 + l15) * 32 + g * 8];
#pragma unroll
    for (int j = 0; j < 4; ++j)
      bfr[j] = *(const bf16x8*)&Bs[(wc * 64 + j * 16 + l15) * 32 + g * 8];
#pragma unroll
    for (int i = 0; i < 4; ++i)
#pragma unroll
      for (int j = 0; j < 4; ++j)
        acc[i][j] = MFMA16(af[i], bfr[j], acc[i][j]);
  }

#pragma unroll
  for (int j = 0; j < 4; ++j) {
    const int n = n0 + wc * 64 + j * 16 + l15;
    const float bv = bias[n];
#pragma unroll
    for (int i = 0; i < 4; ++i) {
      const int mbase = m0 + wr * 64 + i * 16 + g * 4;
#pragma unroll
      for (int r = 0; r < 4; ++r)
        outF[(size_t)(mbase + r) * N + n] = acc[i][j][r] + bv;
    }
  }
}

// ---------------- flash attention (causal), bf16 MFMA --------------
// grid (32 bh, 16 slots), block 512 (8 waves x 16 q-rows = 128-row q-tile),
// KVBLK=128. slot->bx {s, 23-s}. K [s][d] and V^T [d][s] staged by
// global_load_lds with the involution chunk swizzle (source chunk ^ (row&7),
// linear LDS dest, read chunk ^ (row&7)). One __syncthreads per iteration.
// (R9 configuration, measured 47.6 us — best of rounds 8-12.)
__global__ __launch_bounds__(512, 4) void attn_kernel(
    const u16* __restrict__ Qg, const u16* __restrict__ Kg,
    const u16* __restrict__ VTg, u16* __restrict__ Og) {
  __shared__ __align__(16) u16 Ks[2][128 * 64];  // K rows [kv][64 d]
  __shared__ __align__(16) u16 Vs[2][64 * 128];  // V^T rows [d][128 kv]

  const int bh = blockIdx.x;
  const int slot = blockIdx.y;
  const int bx = (slot < 8) ? slot : 23 - slot;
  const int t = threadIdx.x;
  const int lane = t & 63, w = t >> 6;
  const int l15 = lane & 15, g = (lane >> 4) & 3;
  const bool ghi = (lane & 32) != 0;  // dest g>>1
  const int addrA = (l15 + 16 * ((2 * g) & 3)) << 2;      // bperm src, jj<2
  const int addrB = (l15 + 16 * ((2 * g + 1) & 3)) << 2;  // bperm src, jj>=2

  const size_t hb = (size_t)bh * (2048 * 64);
  const u16* Qh = Qg + hb;
  const u16* Kh = Kg + hb;
  const u16* VTh = VTg + hb;
  const int b = bh >> 4, h = bh & 15;

  // K staging (wave w: rows w*16 + {kr8, 8+kr8}; 8 chunks of 8 u16)
  const int kr8 = lane >> 3, cs = lane & 7;
  const int cl = cs ^ kr8;
  // V^T staging (wave w: d-rows {4w..4w+3, 32+4w..32+4w+3}; 16 chunks/row)
  const int vd = 4 * w + (lane >> 4);
  const int vcl = (lane & 15) ^ (vd & 7);  // (vd+32)&7 == vd&7

  const int q0 = bx * 128;
  const int nt = bx + 1;
  const int qrow = q0 + w * 16 + l15;
  const bf16x8 qf0 = *(const bf16x8*)(Qh + (size_t)qrow * 64 + g * 8);
  const bf16x8 qf1 = *(const bf16x8*)(Qh + (size_t)qrow * 64 + 32 + g * 8);

  f32x4 oacc[4] = {};
  float mrow = -1e30f, lrow = 0.f;

#define STAGE(tile, bf)                                                        \
  do {                                                                         \
    const int kv0_ = (tile) * 128;                                             \
    GLDS16(Kh + (size_t)(kv0_ + w * 16 + kr8) * 64 + cl * 8,                   \
           &Ks[bf][w * 1024]);                                                 \
    GLDS16(Kh + (size_t)(kv0_ + w * 16 + 8 + kr8) * 64 + cl * 8,               \
           &Ks[bf][w * 1024 + 512]);                                           \
    GLDS16(VTh + (size_t)vd * 2048 + kv0_ + vcl * 8, &Vs[bf][w * 512]);        \
    GLDS16(VTh + (size_t)(vd + 32) * 2048 + kv0_ + vcl * 8,                    \
           &Vs[bf][w * 512 + 4096]);                                           \
  } while (0)

  STAGE(0, 0);
  __syncthreads();

  for (int kt = 0; kt < nt; ++kt) {
    const int cur = kt & 1;
    if (kt + 1 < nt) STAGE(kt + 1, cur ^ 1);

    // S^T = K Q^T : lane holds S[q=qrow][kv = cf*16 + g*4 + r], cf 0..7
    f32x4 sacc[8];
    const u16* Kc = &Ks[cur][0];
    const int sw = l15 & 7;
#pragma unroll
    for (int cf = 0; cf < 8; ++cf) {
      const int krow = cf * 16 + l15;
      const bf16x8 kf0 = *(const bf16x8*)&Kc[krow * 64 + (g ^ sw) * 8];
      const bf16x8 kf1 = *(const bf16x8*)&Kc[krow * 64 + ((g + 4) ^ sw) * 8];
      f32x4 z = {0.f, 0.f, 0.f, 0.f};
      z = MFMA16(kf0, qf0, z);
      z = MFMA16(kf1, qf1, z);
      sacc[cf] = z;
    }

    if (kt == bx) {  // diagonal 128x128 block: causal mask
      const int kv0 = kt * 128;
#pragma unroll
      for (int cf = 0; cf < 8; ++cf)
#pragma unroll
        for (int r = 0; r < 4; ++r) {
          const int kj = kv0 + cf * 16 + g * 4 + r;
          if (kj > qrow) sacc[cf][r] = -1e30f;
        }
    }

    // row max (tree) + cross-group reduce
    f32x4 m0v = vmax4(vmax4(sacc[0], sacc[1]), vmax4(sacc[2], sacc[3]));
    f32x4 m1v = vmax4(vmax4(sacc[4], sacc[5]), vmax4(sacc[6], sacc[7]));
    f32x4 mv = vmax4(m0v, m1v);
    float tm = fmaxf(fmaxf(mv[0], mv[1]), fmaxf(mv[2], mv[3]));
    tm = fmaxf(tm, __shfl_xor(tm, 16));
    tm = fmaxf(tm, __shfl_xor(tm, 32));

    if (!__all(tm <= mrow)) {  // defer-rescale (sc==1 exactly when skipped)
      const float mn = fmaxf(mrow, tm);
      const float sc = __builtin_amdgcn_exp2f(mrow - mn);
      mrow = mn;
      lrow *= sc;
#pragma unroll
      for (int f = 0; f < 4; ++f) oacc[f] *= sc;
    }

    float rs = 0.f;

#pragma unroll
    for (int hh = 0; hh < 2; ++hh) {
      // exp + pack: pk[cfl][s] covers kv = 64hh + 16cfl + 4g + 2s + {0,1}
      int pk[4][2];
#pragma unroll
      for (int cfl = 0; cfl < 4; ++cfl) {
        const int cf = hh * 4 + cfl;
#pragma unroll
        for (int r = 0; r < 4; ++r) {
          const float p = __builtin_amdgcn_exp2f(sacc[cf][r] - mrow);
          sacc[cf][r] = p;
          rs += p;
        }
#pragma unroll
        for (int s = 0; s < 2; ++s) {
          bf16x2 tp = {(__bf16)sacc[cf][2 * s], (__bf16)sacc[cf][2 * s + 1]};
          pk[cfl][s] = __builtin_bit_cast(int, tp);
        }
      }

#pragma unroll
      for (int clc = 0; clc < 2; ++clc) {
        // P^T B-frag: kv pair 64hh + 32clc + 8g + 2jj; fetch both cf
        // candidates from src lane g'=(2g+(jj>>1))&3, post-select by dest ghi
        int bfr[4];
#pragma unroll
        for (int jj = 0; jj < 4; ++jj) {
          const int addr = (jj >> 1) ? addrB : addrA;
          const int vlo =
              __builtin_amdgcn_ds_bpermute(addr, pk[2 * clc][jj & 1]);
          const int vhi =
              __builtin_amdgcn_ds_bpermute(addr, pk[2 * clc + 1][jj & 1]);
          bfr[jj] = ghi ? vhi : vlo;
        }
        const i32x4 bb = {bfr[0], bfr[1], bfr[2], bfr[3]};
        const bf16x8 pb = __builtin_bit_cast(bf16x8, bb);

        // O^T += V^T P^T ; va[k] = V^T[d = f*16+l15][kv = c*32 + g*8 + k]
        const int c = hh * 2 + clc;
#pragma unroll
        for (int f = 0; f < 4; ++f) {
          const int d = f * 16 + l15;
          const int ch = (c * 4 + g) ^ (d & 7);
          const bf16x8 va = *(const bf16x8*)&Vs[cur][d * 128 + ch * 8];
          oacc[f] = MFMA16(va, pb, oacc[f]);
        }
      }
    }

    rs += __shfl_xor(rs, 16);
    rs += __shfl_xor(rs, 32);
    lrow += rs;

    __syncthreads();  // reads of cur done; next tile's GLDS (vmcnt) drained
  }
#undef STAGE

  // write merged-head O[b][s][h*64 + d], d = f*16 + g*4 + r
  const float inv = 1.f / lrow;
#pragma unroll
  for (int f = 0; f < 4; ++f) {
    ushort4 o;
    o.x = __builtin_bit_cast(u16, (__bf16)(oacc[f][0] * inv));
    o.y = __builtin_bit_cast(u16, (__bf16)(oacc[f][1] * inv));
    o.z = __builtin_bit_cast(u16, (__bf16)(oacc[f][2] * inv));
    o.w = __builtin_bit_cast(u16, (__bf16)(oacc[f][3] * inv));
    *(ushort4*)&Og[((size_t)b * 2048 + qrow) * 1024 + h * 64 + f * 16 +
                   g * 4] = o;
  }
}

extern "C" void kernel_launch(void* const* d_in, const int* in_sizes, int n_in,
                              void* d_out, int out_size, void* d_ws,
                              size_t ws_size, hipStream_t stream) {
  const float* x = (const float*)d_in[0];       // [2,2048,1024]
  const float* w_attn = (const float*)d_in[1];  // [1024,3072]
  const float* b_attn = (const float*)d_in[2];  // [3072]
  const float* w_proj = (const float*)d_in[3];  // [1024,1024]
  const float* b_proj = (const float*)d_in[4];  // [1024]
  float* out = (float*)d_out;                   // [2,2048,1024] fp32

  char* ws = (char*)d_ws;
  u16* xb = (u16*)(ws);                          // 8 MB (reused as O later)
  u16* wT = (u16*)(ws + (8u << 20));             // 6 MB  [3072][1024]
  u16* wpT = (u16*)(ws + (14u << 20));           // 2 MB  [1024][1024]
  u16* Qb = (u16*)(ws + (16u << 20));            // 8 MB  [b][h][s][d]
  u16* Kb = (u16*)(ws + (24u << 20));            // 8 MB  [b][h][s][d]
  u16* VbT = (u16*)(ws + (32u << 20));           // 8 MB  [b][h][d][s]
  u16* Ob = xb;                                  // reuse xb region

  convert_x_kernel<<<4096, 256, 0, stream>>>(x, xb, 1048576);
  transpose_w_kernel<<<dim3(96, 32), 256, 0, stream>>>(w_attn, wT, 1024, 3072);
  transpose_w_kernel<<<dim3(32, 32), 256, 0, stream>>>(w_proj, wpT, 1024, 1024);

  gemm_qkv_kernel<<<dim3(32, 24), 256, 0, stream>>>(xb, wT, b_attn, Qb, Kb,
                                                    VbT, 1024);

  attn_kernel<<<dim3(32, 16), 512, 0, stream>>>(Qb, Kb, VbT, Ob);

  gemm_proj_kernel<<<dim3(32, 8), 256, 0, stream>>>(Ob, wpT, b_proj, out,
                                                    1024, 1024);
}

// Round 14
// 112.296 us; speedup vs baseline: 1.2130x; 1.2130x over previous
//
#include <hip/hip_runtime.h>

typedef unsigned short u16;
typedef __bf16 bf16x8 __attribute__((ext_vector_type(8)));
typedef __bf16 bf16x2 __attribute__((ext_vector_type(2)));
typedef unsigned short u16x8 __attribute__((ext_vector_type(8)));
typedef float f32x4 __attribute__((ext_vector_type(4)));
typedef int i32x4 __attribute__((ext_vector_type(4)));

#define MFMA16(a, b, c) __builtin_amdgcn_mfma_f32_16x16x32_bf16(a, b, c, 0, 0, 0)

#define GLDS16(gp, lp)                                                         \
  __builtin_amdgcn_global_load_lds(                                            \
      (const __attribute__((address_space(1))) unsigned int*)(gp),             \
      (__attribute__((address_space(3))) unsigned int*)(lp), 16, 0, 0)

__device__ __forceinline__ u16 f2bf(float f) {
  unsigned int u = __builtin_bit_cast(unsigned int, f);
  u += 0x7fffu + ((u >> 16) & 1u);
  return (u16)(u >> 16);
}

__device__ __forceinline__ f32x4 vmax4(f32x4 a, f32x4 b) {
  f32x4 r;
  r[0] = fmaxf(a[0], b[0]); r[1] = fmaxf(a[1], b[1]);
  r[2] = fmaxf(a[2], b[2]); r[3] = fmaxf(a[3], b[3]);
  return r;
}

// Q pre-scale: 1/sqrt(64) * log2(e)  (scores produced directly in log2 domain)
#define QSCALE 0.1803368842048386f

// ---------------- elementwise fp32 -> bf16 ----------------
__global__ void convert_x_kernel(const float* __restrict__ src,
                                 u16* __restrict__ dst, int n4) {
  int i = blockIdx.x * 256 + threadIdx.x;
  if (i < n4) {
    float4 v = ((const float4*)src)[i];
    ushort4 o;
    o.x = f2bf(v.x); o.y = f2bf(v.y); o.z = f2bf(v.z); o.w = f2bf(v.w);
    ((ushort4*)dst)[i] = o;
  }
}

// ---------------- transpose fp32 [K][N] -> bf16 [N][K] ----------------
__global__ void transpose_w_kernel(const float* __restrict__ src,
                                   u16* __restrict__ dst, int K, int N) {
  __shared__ float tile[32][33];
  const int n0 = blockIdx.x * 32, k0 = blockIdx.y * 32;
  const int t = threadIdx.x;
  const int r = t >> 3, c = (t & 7) * 4;
  float4 v = *(const float4*)&src[(size_t)(k0 + r) * N + n0 + c];
  tile[r][c + 0] = v.x; tile[r][c + 1] = v.y;
  tile[r][c + 2] = v.z; tile[r][c + 3] = v.w;
  __syncthreads();
  ushort4 o;
  o.x = f2bf(tile[c + 0][r]); o.y = f2bf(tile[c + 1][r]);
  o.z = f2bf(tile[c + 2][r]); o.w = f2bf(tile[c + 3][r]);
  *(ushort4*)&dst[(size_t)(n0 + r) * K + k0 + c] = o;
}

// ---------------- GEMM 128x128, BK=64 (split k-half buffers) ----------------
// qkv epilogue (R9): Q,K head-split [b][h][s][d] (+bias, Q*=QSCALE);
// V stored TRANSPOSED [b][h][d][s] (ushort4 along s).
__global__ __launch_bounds__(256) void gemm_qkv_kernel(
    const u16* __restrict__ A, const u16* __restrict__ Bt,
    const float* __restrict__ bias, u16* __restrict__ Qo,
    u16* __restrict__ Ko, u16* __restrict__ VoT, int K) {
  __shared__ __align__(16) u16 As0[128 * 32];
  __shared__ __align__(16) u16 As1[128 * 32];
  __shared__ __align__(16) u16 Bs0[128 * 32];
  __shared__ __align__(16) u16 Bs1[128 * 32];
  const int t = threadIdx.x;
  const int lane = t & 63;
  const int l15 = lane & 15, g = lane >> 4;
  const int w = t >> 6, wr = w >> 1, wc = w & 1;
  const int m0 = blockIdx.x * 128, n0 = blockIdx.y * 128;
  const int ar = t >> 2, ak = (t & 3) * 8;
  u16* As0W = As0 + (t & ~63) * 8;
  u16* As1W = As1 + (t & ~63) * 8;
  u16* Bs0W = Bs0 + (t & ~63) * 8;
  u16* Bs1W = Bs1 + (t & ~63) * 8;
  const u16* Ag = A + (size_t)(m0 + ar) * K + ak;
  const u16* Bg = Bt + (size_t)(n0 + ar) * K + ak;

  f32x4 acc[4][4] = {};
  for (int k0 = 0; k0 < K; k0 += 64) {
    __syncthreads();
    GLDS16(Ag + k0, As0W);
    GLDS16(Ag + (size_t)64 * K + k0, As0W + 2048);
    GLDS16(Bg + k0, Bs0W);
    GLDS16(Bg + (size_t)64 * K + k0, Bs0W + 2048);
    GLDS16(Ag + k0 + 32, As1W);
    GLDS16(Ag + (size_t)64 * K + k0 + 32, As1W + 2048);
    GLDS16(Bg + k0 + 32, Bs1W);
    GLDS16(Bg + (size_t)64 * K + k0 + 32, Bs1W + 2048);
    __syncthreads();
    {
      bf16x8 af[4], bfr[4];
#pragma unroll
      for (int i = 0; i < 4; ++i)
        af[i] = *(const bf16x8*)&As0[(wr * 64 + i * 16 + l15) * 32 + g * 8];
#pragma unroll
      for (int j = 0; j < 4; ++j)
        bfr[j] = *(const bf16x8*)&Bs0[(wc * 64 + j * 16 + l15) * 32 + g * 8];
#pragma unroll
      for (int i = 0; i < 4; ++i)
#pragma unroll
        for (int j = 0; j < 4; ++j)
          acc[i][j] = MFMA16(af[i], bfr[j], acc[i][j]);
    }
    {
      bf16x8 af[4], bfr[4];
#pragma unroll
      for (int i = 0; i < 4; ++i)
        af[i] = *(const bf16x8*)&As1[(wr * 64 + i * 16 + l15) * 32 + g * 8];
#pragma unroll
      for (int j = 0; j < 4; ++j)
        bfr[j] = *(const bf16x8*)&Bs1[(wc * 64 + j * 16 + l15) * 32 + g * 8];
#pragma unroll
      for (int i = 0; i < 4; ++i)
#pragma unroll
        for (int j = 0; j < 4; ++j)
          acc[i][j] = MFMA16(af[i], bfr[j], acc[i][j]);
    }
  }

#pragma unroll
  for (int j = 0; j < 4; ++j) {
    const int n = n0 + wc * 64 + j * 16 + l15;
    const float bv = bias[n];
    const int part = n >> 10, f = n & 1023;  // part uniform per wave
    const int hh = f >> 6, d = f & 63;
#pragma unroll
    for (int i = 0; i < 4; ++i) {
      const int mbase = m0 + wr * 64 + i * 16 + g * 4;
      const int bq = mbase >> 11, s = mbase & 2047;  // r=0..3 same b, s..s+3
      if (part == 2) {  // V^T: [b][h][d][s], s consecutive -> ushort4
        ushort4 o;
        o.x = f2bf(acc[i][j][0] + bv);
        o.y = f2bf(acc[i][j][1] + bv);
        o.z = f2bf(acc[i][j][2] + bv);
        o.w = f2bf(acc[i][j][3] + bv);
        *(ushort4*)&VoT[(((size_t)(bq * 16 + hh)) * 64 + d) * 2048 + s] = o;
      } else {
        u16* dst = (part == 0) ? Qo : Ko;
        const float sc = (part == 0) ? QSCALE : 1.f;
#pragma unroll
        for (int r = 0; r < 4; ++r)
          dst[(((size_t)(bq * 16 + hh)) * 2048 + (s + r)) * 64 + d] =
              f2bf((acc[i][j][r] + bv) * sc);
      }
    }
  }
}

// ---------------- GEMM 64x128 (proj), BK=64: fp32 out[M][N], +bias ----------
__global__ __launch_bounds__(256) void gemm_proj_kernel(
    const u16* __restrict__ A, const u16* __restrict__ Bt,
    const float* __restrict__ bias, float* __restrict__ outF, int N, int K) {
  __shared__ __align__(16) u16 As0[64 * 32];
  __shared__ __align__(16) u16 As1[64 * 32];
  __shared__ __align__(16) u16 Bs0[128 * 32];
  __shared__ __align__(16) u16 Bs1[128 * 32];
  const int t = threadIdx.x;
  const int lane = t & 63;
  const int l15 = lane & 15, g = lane >> 4;
  const int w = t >> 6, wr = w >> 1, wc = w & 1;
  const int m0 = blockIdx.x * 64, n0 = blockIdx.y * 128;
  const int ar = t >> 2, ak = (t & 3) * 8;
  u16* As0W = As0 + (t & ~63) * 8;
  u16* As1W = As1 + (t & ~63) * 8;
  u16* Bs0W = Bs0 + (t & ~63) * 8;
  u16* Bs1W = Bs1 + (t & ~63) * 8;
  const u16* Ag = A + (size_t)(m0 + ar) * K + ak;
  const u16* Bg = Bt + (size_t)(n0 + ar) * K + ak;

  f32x4 acc[2][4] = {};
  for (int k0 = 0; k0 < K; k0 += 64) {
    __syncthreads();
    GLDS16(Ag + k0, As0W);
    GLDS16(Bg + k0, Bs0W);
    GLDS16(Bg + (size_t)64 * K + k0, Bs0W + 2048);
    GLDS16(Ag + k0 + 32, As1W);
    GLDS16(Bg + k0 + 32, Bs1W);
    GLDS16(Bg + (size_t)64 * K + k0 + 32, Bs1W + 2048);
    __syncthreads();
    {
      bf16x8 af[2], bfr[4];
#pragma unroll
      for (int i = 0; i < 2; ++i)
        af[i] = *(const bf16x8*)&As0[(wr * 32 + i * 16 + l15) * 32 + g * 8];
#pragma unroll
      for (int j = 0; j < 4; ++j)
        bfr[j] = *(const bf16x8*)&Bs0[(wc * 64 + j * 16 + l15) * 32 + g * 8];
#pragma unroll
      for (int i = 0; i < 2; ++i)
#pragma unroll
        for (int j = 0; j < 4; ++j)
          acc[i][j] = MFMA16(af[i], bfr[j], acc[i][j]);
    }
    {
      bf16x8 af[2], bfr[4];
#pragma unroll
      for (int i = 0; i < 2; ++i)
        af[i] = *(const bf16x8*)&As1[(wr * 32 + i * 16 + l15) * 32 + g * 8];
#pragma unroll
      for (int j = 0; j < 4; ++j)
        bfr[j] = *(const bf16x8*)&Bs1[(wc * 64 + j * 16 + l15) * 32 + g * 8];
#pragma unroll
      for (int i = 0; i < 2; ++i)
#pragma unroll
        for (int j = 0; j < 4; ++j)
          acc[i][j] = MFMA16(af[i], bfr[j], acc[i][j]);
    }
  }

#pragma unroll
  for (int j = 0; j < 4; ++j) {
    const int n = n0 + wc * 64 + j * 16 + l15;
    const float bv = bias[n];
#pragma unroll
    for (int i = 0; i < 2; ++i) {
      const int mbase = m0 + wr * 32 + i * 16 + g * 4;
#pragma unroll
      for (int r = 0; r < 4; ++r)
        outF[(size_t)(mbase + r) * N + n] = acc[i][j][r] + bv;
    }
  }
}

// ---------------- flash attention (causal), bf16 MFMA --------------
// R9 configuration verbatim (measured 47.6 us; best of rounds 8-13).
// grid (32 bh, 16 slots), block 512 (8 waves x 16 q-rows = 128-row q-tile),
// KVBLK=128. slot->bx {s, 23-s}. K [s][d] and V^T [d][s] staged by
// global_load_lds with the involution chunk swizzle. One barrier/iter.
__global__ __launch_bounds__(512, 4) void attn_kernel(
    const u16* __restrict__ Qg, const u16* __restrict__ Kg,
    const u16* __restrict__ VTg, u16* __restrict__ Og) {
  __shared__ __align__(16) u16 Ks[2][128 * 64];  // K rows [kv][64 d]
  __shared__ __align__(16) u16 Vs[2][64 * 128];  // V^T rows [d][128 kv]

  const int bh = blockIdx.x;
  const int slot = blockIdx.y;
  const int bx = (slot < 8) ? slot : 23 - slot;
  const int t = threadIdx.x;
  const int lane = t & 63, w = t >> 6;
  const int l15 = lane & 15, g = (lane >> 4) & 3;
  const bool ghi = (lane & 32) != 0;  // dest g>>1
  const int addrA = (l15 + 16 * ((2 * g) & 3)) << 2;      // bperm src, jj<2
  const int addrB = (l15 + 16 * ((2 * g + 1) & 3)) << 2;  // bperm src, jj>=2

  const size_t hb = (size_t)bh * (2048 * 64);
  const u16* Qh = Qg + hb;
  const u16* Kh = Kg + hb;
  const u16* VTh = VTg + hb;
  const int b = bh >> 4, h = bh & 15;

  // K staging (wave w: rows w*16 + {kr8, 8+kr8}; 8 chunks of 8 u16)
  const int kr8 = lane >> 3, cs = lane & 7;
  const int cl = cs ^ kr8;
  // V^T staging (wave w: d-rows {4w..4w+3, 32+4w..32+4w+3}; 16 chunks/row)
  const int vd = 4 * w + (lane >> 4);
  const int vcl = (lane & 15) ^ (vd & 7);  // (vd+32)&7 == vd&7

  const int q0 = bx * 128;
  const int nt = bx + 1;
  const int qrow = q0 + w * 16 + l15;
  const bf16x8 qf0 = *(const bf16x8*)(Qh + (size_t)qrow * 64 + g * 8);
  const bf16x8 qf1 = *(const bf16x8*)(Qh + (size_t)qrow * 64 + 32 + g * 8);

  f32x4 oacc[4] = {};
  float mrow = -1e30f, lrow = 0.f;

#define STAGE(tile, bf)                                                        \
  do {                                                                         \
    const int kv0_ = (tile) * 128;                                             \
    GLDS16(Kh + (size_t)(kv0_ + w * 16 + kr8) * 64 + cl * 8,                   \
           &Ks[bf][w * 1024]);                                                 \
    GLDS16(Kh + (size_t)(kv0_ + w * 16 + 8 + kr8) * 64 + cl * 8,               \
           &Ks[bf][w * 1024 + 512]);                                           \
    GLDS16(VTh + (size_t)vd * 2048 + kv0_ + vcl * 8, &Vs[bf][w * 512]);        \
    GLDS16(VTh + (size_t)(vd + 32) * 2048 + kv0_ + vcl * 8,                    \
           &Vs[bf][w * 512 + 4096]);                                           \
  } while (0)

  STAGE(0, 0);
  __syncthreads();

  for (int kt = 0; kt < nt; ++kt) {
    const int cur = kt & 1;
    if (kt + 1 < nt) STAGE(kt + 1, cur ^ 1);

    // S^T = K Q^T : lane holds S[q=qrow][kv = cf*16 + g*4 + r], cf 0..7
    f32x4 sacc[8];
    const u16* Kc = &Ks[cur][0];
    const int sw = l15 & 7;
#pragma unroll
    for (int cf = 0; cf < 8; ++cf) {
      const int krow = cf * 16 + l15;
      const bf16x8 kf0 = *(const bf16x8*)&Kc[krow * 64 + (g ^ sw) * 8];
      const bf16x8 kf1 = *(const bf16x8*)&Kc[krow * 64 + ((g + 4) ^ sw) * 8];
      f32x4 z = {0.f, 0.f, 0.f, 0.f};
      z = MFMA16(kf0, qf0, z);
      z = MFMA16(kf1, qf1, z);
      sacc[cf] = z;
    }

    if (kt == bx) {  // diagonal 128x128 block: causal mask
      const int kv0 = kt * 128;
#pragma unroll
      for (int cf = 0; cf < 8; ++cf)
#pragma unroll
        for (int r = 0; r < 4; ++r) {
          const int kj = kv0 + cf * 16 + g * 4 + r;
          if (kj > qrow) sacc[cf][r] = -1e30f;
        }
    }

    // row max (tree) + cross-group reduce
    f32x4 m0v = vmax4(vmax4(sacc[0], sacc[1]), vmax4(sacc[2], sacc[3]));
    f32x4 m1v = vmax4(vmax4(sacc[4], sacc[5]), vmax4(sacc[6], sacc[7]));
    f32x4 mv = vmax4(m0v, m1v);
    float tm = fmaxf(fmaxf(mv[0], mv[1]), fmaxf(mv[2], mv[3]));
    tm = fmaxf(tm, __shfl_xor(tm, 16));
    tm = fmaxf(tm, __shfl_xor(tm, 32));

    if (!__all(tm <= mrow)) {  // defer-rescale (sc==1 exactly when skipped)
      const float mn = fmaxf(mrow, tm);
      const float sc = __builtin_amdgcn_exp2f(mrow - mn);
      mrow = mn;
      lrow *= sc;
#pragma unroll
      for (int f = 0; f < 4; ++f) oacc[f] *= sc;
    }

    float rs = 0.f;

#pragma unroll
    for (int hh = 0; hh < 2; ++hh) {
      // exp + pack: pk[cfl][s] covers kv = 64hh + 16cfl + 4g + 2s + {0,1}
      int pk[4][2];
#pragma unroll
      for (int cfl = 0; cfl < 4; ++cfl) {
        const int cf = hh * 4 + cfl;
#pragma unroll
        for (int r = 0; r < 4; ++r) {
          const float p = __builtin_amdgcn_exp2f(sacc[cf][r] - mrow);
          sacc[cf][r] = p;
          rs += p;
        }
#pragma unroll
        for (int s = 0; s < 2; ++s) {
          bf16x2 tp = {(__bf16)sacc[cf][2 * s], (__bf16)sacc[cf][2 * s + 1]};
          pk[cfl][s] = __builtin_bit_cast(int, tp);
        }
      }

#pragma unroll
      for (int clc = 0; clc < 2; ++clc) {
        // P^T B-frag: kv pair 64hh + 32clc + 8g + 2jj; fetch both cf
        // candidates from src lane g'=(2g+(jj>>1))&3, post-select by dest ghi
        int bfr[4];
#pragma unroll
        for (int jj = 0; jj < 4; ++jj) {
          const int addr = (jj >> 1) ? addrB : addrA;
          const int vlo =
              __builtin_amdgcn_ds_bpermute(addr, pk[2 * clc][jj & 1]);
          const int vhi =
              __builtin_amdgcn_ds_bpermute(addr, pk[2 * clc + 1][jj & 1]);
          bfr[jj] = ghi ? vhi : vlo;
        }
        const i32x4 bb = {bfr[0], bfr[1], bfr[2], bfr[3]};
        const bf16x8 pb = __builtin_bit_cast(bf16x8, bb);

        // O^T += V^T P^T ; va[k] = V^T[d = f*16+l15][kv = c*32 + g*8 + k]
        const int c = hh * 2 + clc;
#pragma unroll
        for (int f = 0; f < 4; ++f) {
          const int d = f * 16 + l15;
          const int ch = (c * 4 + g) ^ (d & 7);
          const bf16x8 va = *(const bf16x8*)&Vs[cur][d * 128 + ch * 8];
          oacc[f] = MFMA16(va, pb, oacc[f]);
        }
      }
    }

    rs += __shfl_xor(rs, 16);
    rs += __shfl_xor(rs, 32);
    lrow += rs;

    __syncthreads();  // reads of cur done; next tile's GLDS (vmcnt) drained
  }
#undef STAGE

  // write merged-head O[b][s][h*64 + d], d = f*16 + g*4 + r
  const float inv = 1.f / lrow;
#pragma unroll
  for (int f = 0; f < 4; ++f) {
    ushort4 o;
    o.x = __builtin_bit_cast(u16, (__bf16)(oacc[f][0] * inv));
    o.y = __builtin_bit_cast(u16, (__bf16)(oacc[f][1] * inv));
    o.z = __builtin_bit_cast(u16, (__bf16)(oacc[f][2] * inv));
    o.w = __builtin_bit_cast(u16, (__bf16)(oacc[f][3] * inv));
    *(ushort4*)&Og[((size_t)b * 2048 + qrow) * 1024 + h * 64 + f * 16 +
                   g * 4] = o;
  }
}

extern "C" void kernel_launch(void* const* d_in, const int* in_sizes, int n_in,
                              void* d_out, int out_size, void* d_ws,
                              size_t ws_size, hipStream_t stream) {
  const float* x = (const float*)d_in[0];       // [2,2048,1024]
  const float* w_attn = (const float*)d_in[1];  // [1024,3072]
  const float* b_attn = (const float*)d_in[2];  // [3072]
  const float* w_proj = (const float*)d_in[3];  // [1024,1024]
  const float* b_proj = (const float*)d_in[4];  // [1024]
  float* out = (float*)d_out;                   // [2,2048,1024] fp32

  char* ws = (char*)d_ws;
  u16* xb = (u16*)(ws);                          // 8 MB (reused as O later)
  u16* wT = (u16*)(ws + (8u << 20));             // 6 MB  [3072][1024]
  u16* wpT = (u16*)(ws + (14u << 20));           // 2 MB  [1024][1024]
  u16* Qb = (u16*)(ws + (16u << 20));            // 8 MB  [b][h][s][d]
  u16* Kb = (u16*)(ws + (24u << 20));            // 8 MB  [b][h][s][d]
  u16* VbT = (u16*)(ws + (32u << 20));           // 8 MB  [b][h][d][s]
  u16* Ob = xb;                                  // reuse xb region

  convert_x_kernel<<<4096, 256, 0, stream>>>(x, xb, 1048576);
  transpose_w_kernel<<<dim3(96, 32), 256, 0, stream>>>(w_attn, wT, 1024, 3072);
  transpose_w_kernel<<<dim3(32, 32), 256, 0, stream>>>(w_proj, wpT, 1024, 1024);

  gemm_qkv_kernel<<<dim3(32, 24), 256, 0, stream>>>(xb, wT, b_attn, Qb, Kb,
                                                    VbT, 1024);

  attn_kernel<<<dim3(32, 16), 512, 0, stream>>>(Qb, Kb, VbT, Ob);

  gemm_proj_kernel<<<dim3(64, 8), 256, 0, stream>>>(Ob, wpT, b_proj, out,
                                                    1024, 1024);
}

// Round 15
// 110.744 us; speedup vs baseline: 1.2300x; 1.0140x over previous
//
#include <hip/hip_runtime.h>

typedef unsigned short u16;
typedef __bf16 bf16x8 __attribute__((ext_vector_type(8)));
typedef __bf16 bf16x2 __attribute__((ext_vector_type(2)));
typedef unsigned short u16x8 __attribute__((ext_vector_type(8)));
typedef float f32x4 __attribute__((ext_vector_type(4)));
typedef int i32x4 __attribute__((ext_vector_type(4)));

#define MFMA16(a, b, c) __builtin_amdgcn_mfma_f32_16x16x32_bf16(a, b, c, 0, 0, 0)

#define GLDS16(gp, lp)                                                         \
  __builtin_amdgcn_global_load_lds(                                            \
      (const __attribute__((address_space(1))) unsigned int*)(gp),             \
      (__attribute__((address_space(3))) unsigned int*)(lp), 16, 0, 0)

__device__ __forceinline__ u16 f2bf(float f) {
  unsigned int u = __builtin_bit_cast(unsigned int, f);
  u += 0x7fffu + ((u >> 16) & 1u);
  return (u16)(u >> 16);
}

__device__ __forceinline__ f32x4 vmax4(f32x4 a, f32x4 b) {
  f32x4 r;
  r[0] = fmaxf(a[0], b[0]); r[1] = fmaxf(a[1], b[1]);
  r[2] = fmaxf(a[2], b[2]); r[3] = fmaxf(a[3], b[3]);
  return r;
}

// Q pre-scale: 1/sqrt(64) * log2(e)  (scores produced directly in log2 domain)
#define QSCALE 0.1803368842048386f

// ---------------- fused preprocessing: x->bf16 + both W transposes ----------
// blocks [0,4096): convert x (fp32->bf16, float4/thread)
// blocks [4096,7168): transpose w_attn [1024][3072] -> wT [3072][1024] bf16
// blocks [7168,8192): transpose w_proj [1024][1024] -> wpT [1024][1024] bf16
__global__ __launch_bounds__(256) void preprocess_kernel(
    const float* __restrict__ x, u16* __restrict__ xb,
    const float* __restrict__ w_attn, u16* __restrict__ wT,
    const float* __restrict__ w_proj, u16* __restrict__ wpT) {
  __shared__ float tile[32][33];
  const int blk = blockIdx.x;
  const int t = threadIdx.x;
  if (blk < 4096) {
    const int i = blk * 256 + t;
    float4 v = ((const float4*)x)[i];
    ushort4 o;
    o.x = f2bf(v.x); o.y = f2bf(v.y); o.z = f2bf(v.z); o.w = f2bf(v.w);
    ((ushort4*)xb)[i] = o;
    return;
  }
  const float* src;
  u16* dst;
  int K, N, n0, k0;
  if (blk < 7168) {
    const int id = blk - 4096;
    src = w_attn; dst = wT; K = 1024; N = 3072;
    n0 = (id % 96) * 32; k0 = (id / 96) * 32;
  } else {
    const int id = blk - 7168;
    src = w_proj; dst = wpT; K = 1024; N = 1024;
    n0 = (id & 31) * 32; k0 = (id >> 5) * 32;
  }
  const int r = t >> 3, c = (t & 7) * 4;
  float4 v = *(const float4*)&src[(size_t)(k0 + r) * N + n0 + c];
  tile[r][c + 0] = v.x; tile[r][c + 1] = v.y;
  tile[r][c + 2] = v.z; tile[r][c + 3] = v.w;
  __syncthreads();
  ushort4 o;
  o.x = f2bf(tile[c + 0][r]); o.y = f2bf(tile[c + 1][r]);
  o.z = f2bf(tile[c + 2][r]); o.w = f2bf(tile[c + 3][r]);
  *(ushort4*)&dst[(size_t)(n0 + r) * K + k0 + c] = o;
}

// ---------------- GEMM 128x128, BK=64 (split k-half buffers) ----------------
// qkv epilogue (R9): Q,K head-split [b][h][s][d] (+bias, Q*=QSCALE);
// V stored TRANSPOSED [b][h][d][s] (ushort4 along s).
__global__ __launch_bounds__(256) void gemm_qkv_kernel(
    const u16* __restrict__ A, const u16* __restrict__ Bt,
    const float* __restrict__ bias, u16* __restrict__ Qo,
    u16* __restrict__ Ko, u16* __restrict__ VoT, int K) {
  __shared__ __align__(16) u16 As0[128 * 32];
  __shared__ __align__(16) u16 As1[128 * 32];
  __shared__ __align__(16) u16 Bs0[128 * 32];
  __shared__ __align__(16) u16 Bs1[128 * 32];
  const int t = threadIdx.x;
  const int lane = t & 63;
  const int l15 = lane & 15, g = lane >> 4;
  const int w = t >> 6, wr = w >> 1, wc = w & 1;
  const int m0 = blockIdx.x * 128, n0 = blockIdx.y * 128;
  const int ar = t >> 2, ak = (t & 3) * 8;
  u16* As0W = As0 + (t & ~63) * 8;
  u16* As1W = As1 + (t & ~63) * 8;
  u16* Bs0W = Bs0 + (t & ~63) * 8;
  u16* Bs1W = Bs1 + (t & ~63) * 8;
  const u16* Ag = A + (size_t)(m0 + ar) * K + ak;
  const u16* Bg = Bt + (size_t)(n0 + ar) * K + ak;

  f32x4 acc[4][4] = {};
  for (int k0 = 0; k0 < K; k0 += 64) {
    __syncthreads();
    GLDS16(Ag + k0, As0W);
    GLDS16(Ag + (size_t)64 * K + k0, As0W + 2048);
    GLDS16(Bg + k0, Bs0W);
    GLDS16(Bg + (size_t)64 * K + k0, Bs0W + 2048);
    GLDS16(Ag + k0 + 32, As1W);
    GLDS16(Ag + (size_t)64 * K + k0 + 32, As1W + 2048);
    GLDS16(Bg + k0 + 32, Bs1W);
    GLDS16(Bg + (size_t)64 * K + k0 + 32, Bs1W + 2048);
    __syncthreads();
    {
      bf16x8 af[4], bfr[4];
#pragma unroll
      for (int i = 0; i < 4; ++i)
        af[i] = *(const bf16x8*)&As0[(wr * 64 + i * 16 + l15) * 32 + g * 8];
#pragma unroll
      for (int j = 0; j < 4; ++j)
        bfr[j] = *(const bf16x8*)&Bs0[(wc * 64 + j * 16 + l15) * 32 + g * 8];
#pragma unroll
      for (int i = 0; i < 4; ++i)
#pragma unroll
        for (int j = 0; j < 4; ++j)
          acc[i][j] = MFMA16(af[i], bfr[j], acc[i][j]);
    }
    {
      bf16x8 af[4], bfr[4];
#pragma unroll
      for (int i = 0; i < 4; ++i)
        af[i] = *(const bf16x8*)&As1[(wr * 64 + i * 16 + l15) * 32 + g * 8];
#pragma unroll
      for (int j = 0; j < 4; ++j)
        bfr[j] = *(const bf16x8*)&Bs1[(wc * 64 + j * 16 + l15) * 32 + g * 8];
#pragma unroll
      for (int i = 0; i < 4; ++i)
#pragma unroll
        for (int j = 0; j < 4; ++j)
          acc[i][j] = MFMA16(af[i], bfr[j], acc[i][j]);
    }
  }

#pragma unroll
  for (int j = 0; j < 4; ++j) {
    const int n = n0 + wc * 64 + j * 16 + l15;
    const float bv = bias[n];
    const int part = n >> 10, f = n & 1023;  // part uniform per wave
    const int hh = f >> 6, d = f & 63;
#pragma unroll
    for (int i = 0; i < 4; ++i) {
      const int mbase = m0 + wr * 64 + i * 16 + g * 4;
      const int bq = mbase >> 11, s = mbase & 2047;  // r=0..3 same b, s..s+3
      if (part == 2) {  // V^T: [b][h][d][s], s consecutive -> ushort4
        ushort4 o;
        o.x = f2bf(acc[i][j][0] + bv);
        o.y = f2bf(acc[i][j][1] + bv);
        o.z = f2bf(acc[i][j][2] + bv);
        o.w = f2bf(acc[i][j][3] + bv);
        *(ushort4*)&VoT[(((size_t)(bq * 16 + hh)) * 64 + d) * 2048 + s] = o;
      } else {
        u16* dst = (part == 0) ? Qo : Ko;
        const float sc = (part == 0) ? QSCALE : 1.f;
#pragma unroll
        for (int r = 0; r < 4; ++r)
          dst[(((size_t)(bq * 16 + hh)) * 2048 + (s + r)) * 64 + d] =
              f2bf((acc[i][j][r] + bv) * sc);
      }
    }
  }
}

// ---------------- GEMM 64x128 (proj), BK=64: fp32 out[M][N], +bias ----------
__global__ __launch_bounds__(256) void gemm_proj_kernel(
    const u16* __restrict__ A, const u16* __restrict__ Bt,
    const float* __restrict__ bias, float* __restrict__ outF, int N, int K) {
  __shared__ __align__(16) u16 As0[64 * 32];
  __shared__ __align__(16) u16 As1[64 * 32];
  __shared__ __align__(16) u16 Bs0[128 * 32];
  __shared__ __align__(16) u16 Bs1[128 * 32];
  const int t = threadIdx.x;
  const int lane = t & 63;
  const int l15 = lane & 15, g = lane >> 4;
  const int w = t >> 6, wr = w >> 1, wc = w & 1;
  const int m0 = blockIdx.x * 64, n0 = blockIdx.y * 128;
  const int ar = t >> 2, ak = (t & 3) * 8;
  u16* As0W = As0 + (t & ~63) * 8;
  u16* As1W = As1 + (t & ~63) * 8;
  u16* Bs0W = Bs0 + (t & ~63) * 8;
  u16* Bs1W = Bs1 + (t & ~63) * 8;
  const u16* Ag = A + (size_t)(m0 + ar) * K + ak;
  const u16* Bg = Bt + (size_t)(n0 + ar) * K + ak;

  f32x4 acc[2][4] = {};
  for (int k0 = 0; k0 < K; k0 += 64) {
    __syncthreads();
    GLDS16(Ag + k0, As0W);
    GLDS16(Bg + k0, Bs0W);
    GLDS16(Bg + (size_t)64 * K + k0, Bs0W + 2048);
    GLDS16(Ag + k0 + 32, As1W);
    GLDS16(Bg + k0 + 32, Bs1W);
    GLDS16(Bg + (size_t)64 * K + k0 + 32, Bs1W + 2048);
    __syncthreads();
    {
      bf16x8 af[2], bfr[4];
#pragma unroll
      for (int i = 0; i < 2; ++i)
        af[i] = *(const bf16x8*)&As0[(wr * 32 + i * 16 + l15) * 32 + g * 8];
#pragma unroll
      for (int j = 0; j < 4; ++j)
        bfr[j] = *(const bf16x8*)&Bs0[(wc * 64 + j * 16 + l15) * 32 + g * 8];
#pragma unroll
      for (int i = 0; i < 2; ++i)
#pragma unroll
        for (int j = 0; j < 4; ++j)
          acc[i][j] = MFMA16(af[i], bfr[j], acc[i][j]);
    }
    {
      bf16x8 af[2], bfr[4];
#pragma unroll
      for (int i = 0; i < 2; ++i)
        af[i] = *(const bf16x8*)&As1[(wr * 32 + i * 16 + l15) * 32 + g * 8];
#pragma unroll
      for (int j = 0; j < 4; ++j)
        bfr[j] = *(const bf16x8*)&Bs1[(wc * 64 + j * 16 + l15) * 32 + g * 8];
#pragma unroll
      for (int i = 0; i < 2; ++i)
#pragma unroll
        for (int j = 0; j < 4; ++j)
          acc[i][j] = MFMA16(af[i], bfr[j], acc[i][j]);
    }
  }

#pragma unroll
  for (int j = 0; j < 4; ++j) {
    const int n = n0 + wc * 64 + j * 16 + l15;
    const float bv = bias[n];
#pragma unroll
    for (int i = 0; i < 2; ++i) {
      const int mbase = m0 + wr * 32 + i * 16 + g * 4;
#pragma unroll
      for (int r = 0; r < 4; ++r)
        outF[(size_t)(mbase + r) * N + n] = acc[i][j][r] + bv;
    }
  }
}

// ---------------- flash attention (causal), bf16 MFMA --------------
// R9 configuration + T5 s_setprio around MFMA clusters.
// grid (32 bh, 16 slots), block 512 (8 waves x 16 q-rows = 128-row q-tile),
// KVBLK=128. slot->bx {s, 23-s}. K [s][d] and V^T [d][s] staged by
// global_load_lds with the involution chunk swizzle. One barrier/iter.
__global__ __launch_bounds__(512, 4) void attn_kernel(
    const u16* __restrict__ Qg, const u16* __restrict__ Kg,
    const u16* __restrict__ VTg, u16* __restrict__ Og) {
  __shared__ __align__(16) u16 Ks[2][128 * 64];  // K rows [kv][64 d]
  __shared__ __align__(16) u16 Vs[2][64 * 128];  // V^T rows [d][128 kv]

  const int bh = blockIdx.x;
  const int slot = blockIdx.y;
  const int bx = (slot < 8) ? slot : 23 - slot;
  const int t = threadIdx.x;
  const int lane = t & 63, w = t >> 6;
  const int l15 = lane & 15, g = (lane >> 4) & 3;
  const bool ghi = (lane & 32) != 0;  // dest g>>1
  const int addrA = (l15 + 16 * ((2 * g) & 3)) << 2;      // bperm src, jj<2
  const int addrB = (l15 + 16 * ((2 * g + 1) & 3)) << 2;  // bperm src, jj>=2

  const size_t hb = (size_t)bh * (2048 * 64);
  const u16* Qh = Qg + hb;
  const u16* Kh = Kg + hb;
  const u16* VTh = VTg + hb;
  const int b = bh >> 4, h = bh & 15;

  // K staging (wave w: rows w*16 + {kr8, 8+kr8}; 8 chunks of 8 u16)
  const int kr8 = lane >> 3, cs = lane & 7;
  const int cl = cs ^ kr8;
  // V^T staging (wave w: d-rows {4w..4w+3, 32+4w..32+4w+3}; 16 chunks/row)
  const int vd = 4 * w + (lane >> 4);
  const int vcl = (lane & 15) ^ (vd & 7);  // (vd+32)&7 == vd&7

  const int q0 = bx * 128;
  const int nt = bx + 1;
  const int qrow = q0 + w * 16 + l15;
  const bf16x8 qf0 = *(const bf16x8*)(Qh + (size_t)qrow * 64 + g * 8);
  const bf16x8 qf1 = *(const bf16x8*)(Qh + (size_t)qrow * 64 + 32 + g * 8);

  f32x4 oacc[4] = {};
  float mrow = -1e30f, lrow = 0.f;

#define STAGE(tile, bf)                                                        \
  do {                                                                         \
    const int kv0_ = (tile) * 128;                                             \
    GLDS16(Kh + (size_t)(kv0_ + w * 16 + kr8) * 64 + cl * 8,                   \
           &Ks[bf][w * 1024]);                                                 \
    GLDS16(Kh + (size_t)(kv0_ + w * 16 + 8 + kr8) * 64 + cl * 8,               \
           &Ks[bf][w * 1024 + 512]);                                           \
    GLDS16(VTh + (size_t)vd * 2048 + kv0_ + vcl * 8, &Vs[bf][w * 512]);        \
    GLDS16(VTh + (size_t)(vd + 32) * 2048 + kv0_ + vcl * 8,                    \
           &Vs[bf][w * 512 + 4096]);                                           \
  } while (0)

  STAGE(0, 0);
  __syncthreads();

  for (int kt = 0; kt < nt; ++kt) {
    const int cur = kt & 1;
    if (kt + 1 < nt) STAGE(kt + 1, cur ^ 1);

    // S^T = K Q^T : lane holds S[q=qrow][kv = cf*16 + g*4 + r], cf 0..7
    f32x4 sacc[8];
    const u16* Kc = &Ks[cur][0];
    const int sw = l15 & 7;
    __builtin_amdgcn_s_setprio(1);
#pragma unroll
    for (int cf = 0; cf < 8; ++cf) {
      const int krow = cf * 16 + l15;
      const bf16x8 kf0 = *(const bf16x8*)&Kc[krow * 64 + (g ^ sw) * 8];
      const bf16x8 kf1 = *(const bf16x8*)&Kc[krow * 64 + ((g + 4) ^ sw) * 8];
      f32x4 z = {0.f, 0.f, 0.f, 0.f};
      z = MFMA16(kf0, qf0, z);
      z = MFMA16(kf1, qf1, z);
      sacc[cf] = z;
    }
    __builtin_amdgcn_s_setprio(0);

    if (kt == bx) {  // diagonal 128x128 block: causal mask
      const int kv0 = kt * 128;
#pragma unroll
      for (int cf = 0; cf < 8; ++cf)
#pragma unroll
        for (int r = 0; r < 4; ++r) {
          const int kj = kv0 + cf * 16 + g * 4 + r;
          if (kj > qrow) sacc[cf][r] = -1e30f;
        }
    }

    // row max (tree) + cross-group reduce
    f32x4 m0v = vmax4(vmax4(sacc[0], sacc[1]), vmax4(sacc[2], sacc[3]));
    f32x4 m1v = vmax4(vmax4(sacc[4], sacc[5]), vmax4(sacc[6], sacc[7]));
    f32x4 mv = vmax4(m0v, m1v);
    float tm = fmaxf(fmaxf(mv[0], mv[1]), fmaxf(mv[2], mv[3]));
    tm = fmaxf(tm, __shfl_xor(tm, 16));
    tm = fmaxf(tm, __shfl_xor(tm, 32));

    if (!__all(tm <= mrow)) {  // defer-rescale (sc==1 exactly when skipped)
      const float mn = fmaxf(mrow, tm);
      const float sc = __builtin_amdgcn_exp2f(mrow - mn);
      mrow = mn;
      lrow *= sc;
#pragma unroll
      for (int f = 0; f < 4; ++f) oacc[f] *= sc;
    }

    float rs = 0.f;

#pragma unroll
    for (int hh = 0; hh < 2; ++hh) {
      // exp + pack: pk[cfl][s] covers kv = 64hh + 16cfl + 4g + 2s + {0,1}
      int pk[4][2];
#pragma unroll
      for (int cfl = 0; cfl < 4; ++cfl) {
        const int cf = hh * 4 + cfl;
#pragma unroll
        for (int r = 0; r < 4; ++r) {
          const float p = __builtin_amdgcn_exp2f(sacc[cf][r] - mrow);
          sacc[cf][r] = p;
          rs += p;
        }
#pragma unroll
        for (int s = 0; s < 2; ++s) {
          bf16x2 tp = {(__bf16)sacc[cf][2 * s], (__bf16)sacc[cf][2 * s + 1]};
          pk[cfl][s] = __builtin_bit_cast(int, tp);
        }
      }

#pragma unroll
      for (int clc = 0; clc < 2; ++clc) {
        // P^T B-frag: kv pair 64hh + 32clc + 8g + 2jj; fetch both cf
        // candidates from src lane g'=(2g+(jj>>1))&3, post-select by dest ghi
        int bfr[4];
#pragma unroll
        for (int jj = 0; jj < 4; ++jj) {
          const int addr = (jj >> 1) ? addrB : addrA;
          const int vlo =
              __builtin_amdgcn_ds_bpermute(addr, pk[2 * clc][jj & 1]);
          const int vhi =
              __builtin_amdgcn_ds_bpermute(addr, pk[2 * clc + 1][jj & 1]);
          bfr[jj] = ghi ? vhi : vlo;
        }
        const i32x4 bb = {bfr[0], bfr[1], bfr[2], bfr[3]};
        const bf16x8 pb = __builtin_bit_cast(bf16x8, bb);

        // O^T += V^T P^T ; va[k] = V^T[d = f*16+l15][kv = c*32 + g*8 + k]
        const int c = hh * 2 + clc;
        __builtin_amdgcn_s_setprio(1);
#pragma unroll
        for (int f = 0; f < 4; ++f) {
          const int d = f * 16 + l15;
          const int ch = (c * 4 + g) ^ (d & 7);
          const bf16x8 va = *(const bf16x8*)&Vs[cur][d * 128 + ch * 8];
          oacc[f] = MFMA16(va, pb, oacc[f]);
        }
        __builtin_amdgcn_s_setprio(0);
      }
    }

    rs += __shfl_xor(rs, 16);
    rs += __shfl_xor(rs, 32);
    lrow += rs;

    __syncthreads();  // reads of cur done; next tile's GLDS (vmcnt) drained
  }
#undef STAGE

  // write merged-head O[b][s][h*64 + d], d = f*16 + g*4 + r
  const float inv = 1.f / lrow;
#pragma unroll
  for (int f = 0; f < 4; ++f) {
    ushort4 o;
    o.x = __builtin_bit_cast(u16, (__bf16)(oacc[f][0] * inv));
    o.y = __builtin_bit_cast(u16, (__bf16)(oacc[f][1] * inv));
    o.z = __builtin_bit_cast(u16, (__bf16)(oacc[f][2] * inv));
    o.w = __builtin_bit_cast(u16, (__bf16)(oacc[f][3] * inv));
    *(ushort4*)&Og[((size_t)b * 2048 + qrow) * 1024 + h * 64 + f * 16 +
                   g * 4] = o;
  }
}

extern "C" void kernel_launch(void* const* d_in, const int* in_sizes, int n_in,
                              void* d_out, int out_size, void* d_ws,
                              size_t ws_size, hipStream_t stream) {
  const float* x = (const float*)d_in[0];       // [2,2048,1024]
  const float* w_attn = (const float*)d_in[1];  // [1024,3072]
  const float* b_attn = (const float*)d_in[2];  // [3072]
  const float* w_proj = (const float*)d_in[3];  // [1024,1024]
  const float* b_proj = (const float*)d_in[4];  // [1024]
  float* out = (float*)d_out;                   // [2,2048,1024] fp32

  char* ws = (char*)d_ws;
  u16* xb = (u16*)(ws);                          // 8 MB (reused as O later)
  u16* wT = (u16*)(ws + (8u << 20));             // 6 MB  [3072][1024]
  u16* wpT = (u16*)(ws + (14u << 20));           // 2 MB  [1024][1024]
  u16* Qb = (u16*)(ws + (16u << 20));            // 8 MB  [b][h][s][d]
  u16* Kb = (u16*)(ws + (24u << 20));            // 8 MB  [b][h][s][d]
  u16* VbT = (u16*)(ws + (32u << 20));           // 8 MB  [b][h][d][s]
  u16* Ob = xb;                                  // reuse xb region

  preprocess_kernel<<<8192, 256, 0, stream>>>(x, xb, w_attn, wT, w_proj, wpT);

  gemm_qkv_kernel<<<dim3(32, 24), 256, 0, stream>>>(xb, wT, b_attn, Qb, Kb,
                                                    VbT, 1024);

  attn_kernel<<<dim3(32, 16), 512, 0, stream>>>(Qb, Kb, VbT, Ob);

  gemm_proj_kernel<<<dim3(64, 8), 256, 0, stream>>>(Ob, wpT, b_proj, out,
                                                    1024, 1024);
}

// Round 16
// 102.371 us; speedup vs baseline: 1.3306x; 1.0818x over previous
//
#include <hip/hip_runtime.h>

typedef unsigned short u16;
typedef __bf16 bf16x8 __attribute__((ext_vector_type(8)));
typedef __bf16 bf16x2 __attribute__((ext_vector_type(2)));
typedef float f32x4 __attribute__((ext_vector_type(4)));
typedef float f32x16 __attribute__((ext_vector_type(16)));
typedef int i32x4 __attribute__((ext_vector_type(4)));

#define MFMA16(a, b, c) __builtin_amdgcn_mfma_f32_16x16x32_bf16(a, b, c, 0, 0, 0)
#define MFMA32(a, b, c) __builtin_amdgcn_mfma_f32_32x32x16_bf16(a, b, c, 0, 0, 0)

#define GLDS16(gp, lp)                                                         \
  __builtin_amdgcn_global_load_lds(                                            \
      (const __attribute__((address_space(1))) unsigned int*)(gp),             \
      (__attribute__((address_space(3))) unsigned int*)(lp), 16, 0, 0)

__device__ __forceinline__ u16 f2bf(float f) {
  unsigned int u = __builtin_bit_cast(unsigned int, f);
  u += 0x7fffu + ((u >> 16) & 1u);
  return (u16)(u >> 16);
}

// Q pre-scale: 1/sqrt(64) * log2(e)  (scores produced directly in log2 domain)
#define QSCALE 0.1803368842048386f

// ---------------- fused preprocessing: x->bf16 + both W transposes ----------
__global__ __launch_bounds__(256) void preprocess_kernel(
    const float* __restrict__ x, u16* __restrict__ xb,
    const float* __restrict__ w_attn, u16* __restrict__ wT,
    const float* __restrict__ w_proj, u16* __restrict__ wpT) {
  __shared__ float tile[32][33];
  const int blk = blockIdx.x;
  const int t = threadIdx.x;
  if (blk < 4096) {
    const int i = blk * 256 + t;
    float4 v = ((const float4*)x)[i];
    ushort4 o;
    o.x = f2bf(v.x); o.y = f2bf(v.y); o.z = f2bf(v.z); o.w = f2bf(v.w);
    ((ushort4*)xb)[i] = o;
    return;
  }
  const float* src;
  u16* dst;
  int K, N, n0, k0;
  if (blk < 7168) {
    const int id = blk - 4096;
    src = w_attn; dst = wT; K = 1024; N = 3072;
    n0 = (id % 96) * 32; k0 = (id / 96) * 32;
  } else {
    const int id = blk - 7168;
    src = w_proj; dst = wpT; K = 1024; N = 1024;
    n0 = (id & 31) * 32; k0 = (id >> 5) * 32;
  }
  const int r = t >> 3, c = (t & 7) * 4;
  float4 v = *(const float4*)&src[(size_t)(k0 + r) * N + n0 + c];
  tile[r][c + 0] = v.x; tile[r][c + 1] = v.y;
  tile[r][c + 2] = v.z; tile[r][c + 3] = v.w;
  __syncthreads();
  ushort4 o;
  o.x = f2bf(tile[c + 0][r]); o.y = f2bf(tile[c + 1][r]);
  o.z = f2bf(tile[c + 2][r]); o.w = f2bf(tile[c + 3][r]);
  *(ushort4*)&dst[(size_t)(n0 + r) * K + k0 + c] = o;
}

// ---------------- GEMM 128x128, BK=64 (split k-half buffers) ----------------
// qkv epilogue (R9): Q,K head-split [b][h][s][d] (+bias, Q*=QSCALE);
// V stored TRANSPOSED [b][h][d][s] (ushort4 along s).
__global__ __launch_bounds__(256) void gemm_qkv_kernel(
    const u16* __restrict__ A, const u16* __restrict__ Bt,
    const float* __restrict__ bias, u16* __restrict__ Qo,
    u16* __restrict__ Ko, u16* __restrict__ VoT, int K) {
  __shared__ __align__(16) u16 As0[128 * 32];
  __shared__ __align__(16) u16 As1[128 * 32];
  __shared__ __align__(16) u16 Bs0[128 * 32];
  __shared__ __align__(16) u16 Bs1[128 * 32];
  const int t = threadIdx.x;
  const int lane = t & 63;
  const int l15 = lane & 15, g = lane >> 4;
  const int w = t >> 6, wr = w >> 1, wc = w & 1;
  const int m0 = blockIdx.x * 128, n0 = blockIdx.y * 128;
  const int ar = t >> 2, ak = (t & 3) * 8;
  u16* As0W = As0 + (t & ~63) * 8;
  u16* As1W = As1 + (t & ~63) * 8;
  u16* Bs0W = Bs0 + (t & ~63) * 8;
  u16* Bs1W = Bs1 + (t & ~63) * 8;
  const u16* Ag = A + (size_t)(m0 + ar) * K + ak;
  const u16* Bg = Bt + (size_t)(n0 + ar) * K + ak;

  f32x4 acc[4][4] = {};
  for (int k0 = 0; k0 < K; k0 += 64) {
    __syncthreads();
    GLDS16(Ag + k0, As0W);
    GLDS16(Ag + (size_t)64 * K + k0, As0W + 2048);
    GLDS16(Bg + k0, Bs0W);
    GLDS16(Bg + (size_t)64 * K + k0, Bs0W + 2048);
    GLDS16(Ag + k0 + 32, As1W);
    GLDS16(Ag + (size_t)64 * K + k0 + 32, As1W + 2048);
    GLDS16(Bg + k0 + 32, Bs1W);
    GLDS16(Bg + (size_t)64 * K + k0 + 32, Bs1W + 2048);
    __syncthreads();
    {
      bf16x8 af[4], bfr[4];
#pragma unroll
      for (int i = 0; i < 4; ++i)
        af[i] = *(const bf16x8*)&As0[(wr * 64 + i * 16 + l15) * 32 + g * 8];
#pragma unroll
      for (int j = 0; j < 4; ++j)
        bfr[j] = *(const bf16x8*)&Bs0[(wc * 64 + j * 16 + l15) * 32 + g * 8];
#pragma unroll
      for (int i = 0; i < 4; ++i)
#pragma unroll
        for (int j = 0; j < 4; ++j)
          acc[i][j] = MFMA16(af[i], bfr[j], acc[i][j]);
    }
    {
      bf16x8 af[4], bfr[4];
#pragma unroll
      for (int i = 0; i < 4; ++i)
        af[i] = *(const bf16x8*)&As1[(wr * 64 + i * 16 + l15) * 32 + g * 8];
#pragma unroll
      for (int j = 0; j < 4; ++j)
        bfr[j] = *(const bf16x8*)&Bs1[(wc * 64 + j * 16 + l15) * 32 + g * 8];
#pragma unroll
      for (int i = 0; i < 4; ++i)
#pragma unroll
        for (int j = 0; j < 4; ++j)
          acc[i][j] = MFMA16(af[i], bfr[j], acc[i][j]);
    }
  }

#pragma unroll
  for (int j = 0; j < 4; ++j) {
    const int n = n0 + wc * 64 + j * 16 + l15;
    const float bv = bias[n];
    const int part = n >> 10, f = n & 1023;  // part uniform per wave
    const int hh = f >> 6, d = f & 63;
#pragma unroll
    for (int i = 0; i < 4; ++i) {
      const int mbase = m0 + wr * 64 + i * 16 + g * 4;
      const int bq = mbase >> 11, s = mbase & 2047;  // r=0..3 same b, s..s+3
      if (part == 2) {  // V^T: [b][h][d][s], s consecutive -> ushort4
        ushort4 o;
        o.x = f2bf(acc[i][j][0] + bv);
        o.y = f2bf(acc[i][j][1] + bv);
        o.z = f2bf(acc[i][j][2] + bv);
        o.w = f2bf(acc[i][j][3] + bv);
        *(ushort4*)&VoT[(((size_t)(bq * 16 + hh)) * 64 + d) * 2048 + s] = o;
      } else {
        u16* dst = (part == 0) ? Qo : Ko;
        const float sc = (part == 0) ? QSCALE : 1.f;
#pragma unroll
        for (int r = 0; r < 4; ++r)
          dst[(((size_t)(bq * 16 + hh)) * 2048 + (s + r)) * 64 + d] =
              f2bf((acc[i][j][r] + bv) * sc);
      }
    }
  }
}

// ---------------- GEMM 64x128 (proj), BK=64: fp32 out[M][N], +bias ----------
__global__ __launch_bounds__(256) void gemm_proj_kernel(
    const u16* __restrict__ A, const u16* __restrict__ Bt,
    const float* __restrict__ bias, float* __restrict__ outF, int N, int K) {
  __shared__ __align__(16) u16 As0[64 * 32];
  __shared__ __align__(16) u16 As1[64 * 32];
  __shared__ __align__(16) u16 Bs0[128 * 32];
  __shared__ __align__(16) u16 Bs1[128 * 32];
  const int t = threadIdx.x;
  const int lane = t & 63;
  const int l15 = lane & 15, g = lane >> 4;
  const int w = t >> 6, wr = w >> 1, wc = w & 1;
  const int m0 = blockIdx.x * 64, n0 = blockIdx.y * 128;
  const int ar = t >> 2, ak = (t & 3) * 8;
  u16* As0W = As0 + (t & ~63) * 8;
  u16* As1W = As1 + (t & ~63) * 8;
  u16* Bs0W = Bs0 + (t & ~63) * 8;
  u16* Bs1W = Bs1 + (t & ~63) * 8;
  const u16* Ag = A + (size_t)(m0 + ar) * K + ak;
  const u16* Bg = Bt + (size_t)(n0 + ar) * K + ak;

  f32x4 acc[2][4] = {};
  for (int k0 = 0; k0 < K; k0 += 64) {
    __syncthreads();
    GLDS16(Ag + k0, As0W);
    GLDS16(Bg + k0, Bs0W);
    GLDS16(Bg + (size_t)64 * K + k0, Bs0W + 2048);
    GLDS16(Ag + k0 + 32, As1W);
    GLDS16(Bg + k0 + 32, Bs1W);
    GLDS16(Bg + (size_t)64 * K + k0 + 32, Bs1W + 2048);
    __syncthreads();
    {
      bf16x8 af[2], bfr[4];
#pragma unroll
      for (int i = 0; i < 2; ++i)
        af[i] = *(const bf16x8*)&As0[(wr * 32 + i * 16 + l15) * 32 + g * 8];
#pragma unroll
      for (int j = 0; j < 4; ++j)
        bfr[j] = *(const bf16x8*)&Bs0[(wc * 64 + j * 16 + l15) * 32 + g * 8];
#pragma unroll
      for (int i = 0; i < 2; ++i)
#pragma unroll
        for (int j = 0; j < 4; ++j)
          acc[i][j] = MFMA16(af[i], bfr[j], acc[i][j]);
    }
    {
      bf16x8 af[2], bfr[4];
#pragma unroll
      for (int i = 0; i < 2; ++i)
        af[i] = *(const bf16x8*)&As1[(wr * 32 + i * 16 + l15) * 32 + g * 8];
#pragma unroll
      for (int j = 0; j < 4; ++j)
        bfr[j] = *(const bf16x8*)&Bs1[(wc * 64 + j * 16 + l15) * 32 + g * 8];
#pragma unroll
      for (int i = 0; i < 2; ++i)
#pragma unroll
        for (int j = 0; j < 4; ++j)
          acc[i][j] = MFMA16(af[i], bfr[j], acc[i][j]);
    }
  }

#pragma unroll
  for (int j = 0; j < 4; ++j) {
    const int n = n0 + wc * 64 + j * 16 + l15;
    const float bv = bias[n];
#pragma unroll
    for (int i = 0; i < 2; ++i) {
      const int mbase = m0 + wr * 32 + i * 16 + g * 4;
#pragma unroll
      for (int r = 0; r < 4; ++r)
        outF[(size_t)(mbase + r) * N + n] = acc[i][j][r] + bv;
    }
  }
}

// ---------------- flash attention (causal), 32x32x16 MFMA ------------------
// grid (32 bh, 16 slots), block 512 = 8 waves: wave = (q-block wq = w>>1 of
// 32 rows, kv-half kvh = w&1 of 64). q-tile 128, KVBLK=128, slot->bx {s,23-s}.
// K and V^T staged into FRAGMENT-ORDERED LDS (1KB per MFMA fragment, lane-
// linear) via per-lane GLDS source addressing -> conflict-free ds_read_b128.
// Swapped QK^T (S^T = K Q^T) with 32x32: lane owns q=lane&31, 16 kv/lane;
// softmax in-lane + shfl_xor(32). P->PV-B-frag via 2 shfl_xor(32)/slice.
// Per-wave independent online softmax over its kv-half; wave pairs merged
// in an LDS epilogue (flash-decoding style).
__global__ __launch_bounds__(512, 2) void attn_kernel(
    const u16* __restrict__ Qg, const u16* __restrict__ Kg,
    const u16* __restrict__ VTg, u16* __restrict__ Og) {
  __shared__ __align__(16) u16 LB[32768];  // 64 KB
  // K frag (buf,fk):  LB[buf*8192 + fk*512],  fk = kb*4+ks  (kb kv-32, ks d-16)
  // V frag (buf,fv):  LB[16384 + buf*8192 + fv*512], fv = db*8+kvs
  const int bh = blockIdx.x;
  const int slot = blockIdx.y;
  const int bx = (slot < 8) ? slot : 23 - slot;
  const int t = threadIdx.x;
  const int lane = t & 63, w = t >> 6;
  const int q31 = lane & 31, h = lane >> 5;
  const int wq = w >> 1;   // q-block 0..3
  const int kvh = w & 1;   // kv-half 0..1

  const size_t hb = (size_t)bh * (2048 * 64);
  const u16* Qh = Qg + hb;
  const u16* Kh = Kg + hb;
  const u16* VTh = VTg + hb;
  const int b = bh >> 4, hd = bh & 15;

  const int q0 = bx * 128;
  const int nt = bx + 1;
  const int qrow = q0 + 32 * wq + q31;

  // Q fragments (B-operand): qf[ks] = Q[qrow][8h + 16ks .. +7]
  bf16x8 qf[4];
#pragma unroll
  for (int ks = 0; ks < 4; ++ks)
    qf[ks] = *(const bf16x8*)(Qh + (size_t)qrow * 64 + 8 * h + 16 * ks);

  // staging: wave w stages K frags {2w,2w+1} and V frags {2w,2w+1}
  const int fk0 = 2 * w;

#define STAGE(tile, bf)                                                        \
  do {                                                                         \
    const int kv0_ = (tile) * 128;                                             \
    _Pragma("unroll") for (int ff = 0; ff < 2; ++ff) {                         \
      const int fi = fk0 + ff;                                                 \
      const int kb_ = fi >> 2, ks_ = fi & 3;                                   \
      GLDS16(Kh + (size_t)(kv0_ + 32 * kb_ + q31) * 64 + 8 * h + 16 * ks_,     \
             &LB[(bf) * 8192 + fi * 512]);                                     \
      const int db_ = fi >> 3, kvs_ = fi & 7;                                  \
      GLDS16(                                                                  \
          VTh + (size_t)(32 * db_ + q31) * 2048 + kv0_ + 8 * h + 16 * kvs_,    \
          &LB[16384 + (bf) * 8192 + fi * 512]);                                \
    }                                                                          \
  } while (0)

  f32x16 oacc[2] = {};
  float mrow = -1e30f, lrow = 0.f;

  STAGE(0, 0);
  __syncthreads();

  for (int kt = 0; kt < nt; ++kt) {
    const int cur = kt & 1;
    if (kt + 1 < nt) STAGE(kt + 1, cur ^ 1);
    const u16* Kc = &LB[cur * 8192];
    const u16* Vc = &LB[16384 + cur * 8192];

    // S^T = K Q^T : sacc[kb] is the 32kv x 32q block (kb local to kv-half)
    f32x16 sacc[2];
#pragma unroll
    for (int kb = 0; kb < 2; ++kb) {
      f32x16 z = {};
#pragma unroll
      for (int ks = 0; ks < 4; ++ks) {
        const int fi = (2 * kvh + kb) * 4 + ks;
        const bf16x8 kfr = *(const bf16x8*)&Kc[fi * 512 + lane * 8];
        z = MFMA32(kfr, qf[ks], z);
      }
      sacc[kb] = z;
    }

    if (kt == bx) {  // diagonal tile: causal mask
      const int kvb = kt * 128 + 64 * kvh + 4 * h;
#pragma unroll
      for (int kb = 0; kb < 2; ++kb)
#pragma unroll
        for (int r = 0; r < 16; ++r) {
          const int kj = kvb + 32 * kb + (r & 3) + 8 * (r >> 2);
          if (kj > qrow) sacc[kb][r] = -1e30f;
        }
    }

    // row stats: in-lane over 32 + pair-lane via shfl_xor(32)
    float tm = -1e30f;
#pragma unroll
    for (int kb = 0; kb < 2; ++kb)
#pragma unroll
      for (int r = 0; r < 16; ++r) tm = fmaxf(tm, sacc[kb][r]);
    tm = fmaxf(tm, __shfl_xor(tm, 32));

    if (!__all(tm <= mrow)) {  // defer-rescale (sc==1 exactly when skipped)
      const float mn = fmaxf(mrow, tm);
      const float sc = __builtin_amdgcn_exp2f(mrow - mn);
      mrow = mn;
      lrow *= sc;
      oacc[0] *= sc;
      oacc[1] *= sc;
    }

    float rs = 0.f;
    int pk[2][8];
#pragma unroll
    for (int kb = 0; kb < 2; ++kb) {
#pragma unroll
      for (int r = 0; r < 16; ++r) {
        const float p = __builtin_amdgcn_exp2f(sacc[kb][r] - mrow);
        sacc[kb][r] = p;
        rs += p;
      }
#pragma unroll
      for (int i = 0; i < 8; ++i) {
        bf16x2 tp = {(__bf16)sacc[kb][2 * i], (__bf16)sacc[kb][2 * i + 1]};
        pk[kb][i] = __builtin_bit_cast(int, tp);
      }
    }
    rs += __shfl_xor(rs, 32);
    lrow += rs;

    // PV: O^T[d][q] += V^T-frag x P^T-frag
#pragma unroll
    for (int kb = 0; kb < 2; ++kb) {
#pragma unroll
      for (int s = 0; s < 2; ++s) {
        const int base = 4 * s;
        const int pass0 = h ? pk[kb][base] : pk[kb][base + 2];
        const int pass1 = h ? pk[kb][base + 1] : pk[kb][base + 3];
        const int rx0 = __shfl_xor(pass0, 32);
        const int rx1 = __shfl_xor(pass1, 32);
        const int own0 = h ? pk[kb][base + 2] : pk[kb][base];
        const int own1 = h ? pk[kb][base + 3] : pk[kb][base + 1];
        i32x4 bb;
        bb[0] = h ? rx0 : own0;
        bb[1] = h ? rx1 : own1;
        bb[2] = h ? own0 : rx0;
        bb[3] = h ? own1 : rx1;
        const bf16x8 pb = __builtin_bit_cast(bf16x8, bb);
        const int kvs = 4 * kvh + 2 * kb + s;
#pragma unroll
        for (int db = 0; db < 2; ++db) {
          const int fv = db * 8 + kvs;
          const bf16x8 va = *(const bf16x8*)&Vc[fv * 512 + lane * 8];
          oacc[db] = MFMA32(va, pb, oacc[db]);
        }
      }
    }

    __syncthreads();  // reads of cur done; next tile's GLDS (vmcnt) drained
  }
#undef STAGE

  // ---- merge wave pairs (same wq, kvh 0/1) via LDS ----
  float* ML = (float*)&LB[30720];  // 8 waves x 64 lanes x 2 f32 = 4 KB
  float* OL = (float*)&LB[0];      // 4 qb x (64 lanes x 33) f32 = 33.8 KB
  ML[(w * 64 + lane) * 2] = mrow;
  ML[(w * 64 + lane) * 2 + 1] = lrow;
  __syncthreads();
  const int wp = w ^ 1;
  const float m_p = ML[(wp * 64 + lane) * 2];
  const float l_p = ML[(wp * 64 + lane) * 2 + 1];
  const float mstar = fmaxf(mrow, m_p);
  const float al = __builtin_amdgcn_exp2f(mrow - mstar);
  const float lstar =
      al * lrow + __builtin_amdgcn_exp2f(m_p - mstar) * l_p;
  if (kvh == 1) {
    float* dst = OL + wq * 2112 + lane * 33;
#pragma unroll
    for (int db = 0; db < 2; ++db)
#pragma unroll
      for (int r = 0; r < 16; ++r) dst[db * 16 + r] = al * oacc[db][r];
  }
  __syncthreads();
  if (kvh == 0) {
    const float inv = 1.f / lstar;
    const float* src = OL + wq * 2112 + lane * 33;
    // O[b][qrow][hd*64 + d], d = (r&3) + 8*(r>>2) + 4h + 32db
#pragma unroll
    for (int db = 0; db < 2; ++db) {
#pragma unroll
      for (int rq = 0; rq < 4; ++rq) {
        ushort4 o;
#pragma unroll
        for (int rr = 0; rr < 4; ++rr) {
          const int r = rq * 4 + rr;
          const float v = (al * oacc[db][r] + src[db * 16 + r]) * inv;
          ((u16*)&o)[rr] = f2bf(v);
        }
        const int dbase = 32 * db + 8 * rq + 4 * h;
        *(ushort4*)&Og[((size_t)b * 2048 + qrow) * 1024 + hd * 64 + dbase] = o;
      }
    }
  }
}

extern "C" void kernel_launch(void* const* d_in, const int* in_sizes, int n_in,
                              void* d_out, int out_size, void* d_ws,
                              size_t ws_size, hipStream_t stream) {
  const float* x = (const float*)d_in[0];       // [2,2048,1024]
  const float* w_attn = (const float*)d_in[1];  // [1024,3072]
  const float* b_attn = (const float*)d_in[2];  // [3072]
  const float* w_proj = (const float*)d_in[3];  // [1024,1024]
  const float* b_proj = (const float*)d_in[4];  // [1024]
  float* out = (float*)d_out;                   // [2,2048,1024] fp32

  char* ws = (char*)d_ws;
  u16* xb = (u16*)(ws);                          // 8 MB (reused as O later)
  u16* wT = (u16*)(ws + (8u << 20));             // 6 MB  [3072][1024]
  u16* wpT = (u16*)(ws + (14u << 20));           // 2 MB  [1024][1024]
  u16* Qb = (u16*)(ws + (16u << 20));            // 8 MB  [b][h][s][d]
  u16* Kb = (u16*)(ws + (24u << 20));            // 8 MB  [b][h][s][d]
  u16* VbT = (u16*)(ws + (32u << 20));           // 8 MB  [b][h][d][s]
  u16* Ob = xb;                                  // reuse xb region

  preprocess_kernel<<<8192, 256, 0, stream>>>(x, xb, w_attn, wT, w_proj, wpT);

  gemm_qkv_kernel<<<dim3(32, 24), 256, 0, stream>>>(xb, wT, b_attn, Qb, Kb,
                                                    VbT, 1024);

  attn_kernel<<<dim3(32, 16), 512, 0, stream>>>(Qb, Kb, VbT, Ob);

  gemm_proj_kernel<<<dim3(64, 8), 256, 0, stream>>>(Ob, wpT, b_proj, out,
                                                    1024, 1024);
}